// Round 1
// baseline (759.987 us; speedup 1.0000x reference)
//
#include <hip/hip_runtime.h>

#define T     8192
#define DH    64
#define TMASK 8191
#define SCALE 0.044194173824159216f   // (h*dh)^-0.5 = 512^-0.5
#define NEGF  -3.402823466e38f

static __device__ __forceinline__ unsigned short f2bf(float f) {
  unsigned int u = __float_as_uint(f);
  u += 0x7fffu + ((u >> 16) & 1u);      // round-to-nearest-even
  return (unsigned short)(u >> 16);
}
static __device__ __forceinline__ float bf2f(unsigned short s) {
  return __uint_as_float(((unsigned int)s) << 16);
}

// ---------------------------------------------------------------------------
// Kernel A1: per-segment (bucket) sums of rotated k. grid = 64 bh * 32 chunks.
// segs[bhi][sg][c] = sum_{s=0..63} k_rot[bhi][sg*64+s][c]
// ---------------------------------------------------------------------------
__global__ void __launch_bounds__(256) seg_sums_kernel(
    const float* __restrict__ k, float* __restrict__ segs) {
  int bid = blockIdx.x;
  int bhi = bid >> 5;
  int ch  = bid & 31;
  int hd  = bhi & 7;
  bool rot = hd >= 4;
  int tid = threadIdx.x;
  int sgl = tid >> 6;      // 0..3
  int c   = tid & 63;
  int sg  = ch * 4 + sgl;  // 0..127
  const float* kb = k + (size_t)bhi * T * DH;
  float sum = 0.f;
  int t0 = sg * 64;
  for (int s = 0; s < 64; ++s) {
    int t  = t0 + s;
    int st = rot ? ((t + 63) & TMASK) : t;
    sum += kb[(size_t)st * DH + c];
  }
  segs[((size_t)bhi * 128 + sg) * 64 + c] = sum;
}

// ---------------------------------------------------------------------------
// Kernel A2: per-bh routing. grid = 64 blocks.
// Builds X[u] = [cumavg_k(u*64), k(u*64)] (128 dims), computes
// R = leaky_relu(X @ W), causal mask -> softmax -> strict-lower -> top-1.
// Emits routeIdx (0 = null bucket, v>=1 = bucket v-1) and routeP (weight).
// ---------------------------------------------------------------------------
__global__ void __launch_bounds__(256) route_kernel(
    const float* __restrict__ k, const float* __restrict__ sortW,
    const float* __restrict__ segs,
    int* __restrict__ routeIdx, float* __restrict__ routeP) {
  __shared__ float sX[128][128];   // 64 KB
  int bhi = blockIdx.x;
  int hd  = bhi & 7;
  bool rot = hd >= 4;
  int tid = threadIdx.x;
  const float* kb = k + (size_t)bhi * T * DH;

  // Phase 1: prefix over segment sums; X features. threads 0..63 = channel c.
  if (tid < 64) {
    int c = tid;
    float run = 0.f;   // exclusive prefix: sum of full segments 0..u-1
    for (int u = 0; u < 128; ++u) {
      int t  = u * 64;
      int st = rot ? ((t + 63) & TMASK) : t;
      float first = kb[(size_t)st * DH + c];
      sX[u][64 + c] = first;                       // raw k at bucket start
      sX[u][c] = (run + first) / (float)(t + 1);   // inclusive cumavg
      run += segs[((size_t)bhi * 128 + u) * 64 + c];
    }
  }
  __syncthreads();

  // Phase 2: one wave per row u. lane handles cols c = lane, lane+64.
  // Col 128 is always masked (cols >= rows+1), never needed.
  int lane = tid & 63;
  int w    = tid >> 6;
  const float* Wh = sortW + (size_t)hd * 128 * 129;
  for (int rr = 0; rr < 32; ++rr) {
    int u = rr * 4 + w;
    int c0 = lane, c1 = lane + 64;
    float z0 = 0.f, z1 = 0.f;
    for (int dd = 0; dd < 128; ++dd) {
      float xv = sX[u][dd];
      const float* wrow = Wh + (size_t)dd * 129;
      z0 = fmaf(xv, wrow[c0], z0);
      z1 = fmaf(xv, wrow[c1], z1);
    }
    // leaky_relu (slope 0.01)
    float l0 = z0 >= 0.f ? z0 : 0.01f * z0;
    float l1 = z1 >= 0.f ? z1 : 0.01f * z1;
    bool a0 = (c0 <= u), a1 = (c1 <= u);   // softmax support (incl. diagonal)
    float m = fmaxf(a0 ? l0 : NEGF, a1 ? l1 : NEGF);
    for (int off = 32; off; off >>= 1) m = fmaxf(m, __shfl_xor(m, off));
    float se = (a0 ? __expf(l0 - m) : 0.f) + (a1 ? __expf(l1 - m) : 0.f);
    for (int off = 32; off; off >>= 1) se += __shfl_xor(se, off);
    // argmax over strict-lower (c < u), first-index tie-break
    float bv = NEGF; int bi = 0x7fffffff;
    if (c0 < u && l0 > bv) { bv = l0; bi = c0; }
    if (c1 < u && (l1 > bv || (l1 == bv && c1 < bi))) { bv = l1; bi = c1; }
    for (int off = 32; off; off >>= 1) {
      float ov = __shfl_xor(bv, off); int oi = __shfl_xor(bi, off);
      if (ov > bv || (ov == bv && oi < bi)) { bv = ov; bi = oi; }
    }
    if (lane == 0) {
      if (u == 0) { routeIdx[bhi * 128] = 0; routeP[bhi * 128] = 0.f; }
      else {
        routeIdx[bhi * 128 + u] = bi;
        routeP[bhi * 128 + u]   = __expf(bv - m) / se;
      }
    }
  }
}

// ---------------------------------------------------------------------------
// Kernel B: main attention. grid = bh*buckets = 8192 blocks, 256 threads.
// Per block: Q(64x64) vs K2(128x64) [routed(0..63) + causal(64..127)],
// mask, softmax, P @ V2, write (with inverse head rotation).
// LDS layout (59392 B total, 2 blocks/CU):
//   sQ  bf16 [64][64]          bytes     0 .. 8191
//   sK  f32  [128][68] (pad)   bytes  8192 .. 43007
//   sV  bf16 [128][64]         bytes 43008 .. 59391
//   sP  f32  [64][132] (pad)   bytes     0 .. 33791 (aliases sQ+sK, dead)
// ---------------------------------------------------------------------------
__global__ void __launch_bounds__(256, 2) attn_kernel(
    const float* __restrict__ q, const float* __restrict__ k,
    const float* __restrict__ v,
    const float* __restrict__ nullk, const float* __restrict__ nullv,
    const int* __restrict__ routeIdx, const float* __restrict__ routeP,
    float* __restrict__ out) {
  __shared__ __align__(16) float smem[14848];
  unsigned short* sQ = (unsigned short*)smem;                       // [64][64]
  float*          sK = smem + 2048;                                 // [128][68]
  unsigned short* sV = (unsigned short*)((char*)smem + 43008);      // [128][64]
  float*          sP = smem;                                        // [64][132]

  int bid = blockIdx.x;
  int u   = bid & 127;
  int bhi = bid >> 7;
  int hd  = bhi & 7;
  bool rot = hd >= 4;
  int tid = threadIdx.x;
  const float* qb = q + (size_t)bhi * T * DH;
  const float* kb = k + (size_t)bhi * T * DH;
  const float* vb = v + (size_t)bhi * T * DH;
  float* ob = out + (size_t)bhi * T * DH;
  int   ridx = routeIdx[bhi * 128 + u];
  float p    = routeP[bhi * 128 + u];
  const float* nkh = nullk + hd * DH;
  const float* nvh = nullv + hd * DH;

  // ---- load Q (scaled, bf16) ----
  for (int it = 0; it < 4; ++it) {
    int flat = it * 256 + tid;          // 0..1023
    int row = flat >> 4;
    int c4  = (flat & 15) << 2;
    int t   = u * 64 + row;
    int st  = rot ? ((t + 63) & TMASK) : t;
    float4 qv = *(const float4*)(qb + (size_t)st * DH + c4);
    ushort4 o4;
    o4.x = f2bf(qv.x * SCALE); o4.y = f2bf(qv.y * SCALE);
    o4.z = f2bf(qv.z * SCALE); o4.w = f2bf(qv.w * SCALE);
    *(ushort4*)(sQ + row * 64 + c4) = o4;
  }
  // ---- load K (rows 0..63 routed*p, 64..127 causal), fp32 ----
  for (int it = 0; it < 8; ++it) {
    int flat = it * 256 + tid;          // 0..2047
    int row = flat >> 4;
    int c4  = (flat & 15) << 2;
    float4 kv;
    if (row < 64) {
      if (ridx == 0) kv = *(const float4*)(nkh + c4);
      else {
        int t = (ridx - 1) * 64 + row;
        int st = rot ? ((t + 63) & TMASK) : t;
        kv = *(const float4*)(kb + (size_t)st * DH + c4);
      }
      kv.x *= p; kv.y *= p; kv.z *= p; kv.w *= p;
    } else {
      int t = u * 64 + (row - 64);
      int st = rot ? ((t + 63) & TMASK) : t;
      kv = *(const float4*)(kb + (size_t)st * DH + c4);
    }
    *(float4*)(sK + row * 68 + c4) = kv;
  }
  // ---- load V (same layout), bf16 ----
  for (int it = 0; it < 8; ++it) {
    int flat = it * 256 + tid;
    int row = flat >> 4;
    int c4  = (flat & 15) << 2;
    float4 vv;
    if (row < 64) {
      if (ridx == 0) vv = *(const float4*)(nvh + c4);
      else {
        int t = (ridx - 1) * 64 + row;
        int st = rot ? ((t + 63) & TMASK) : t;
        vv = *(const float4*)(vb + (size_t)st * DH + c4);
      }
      vv.x *= p; vv.y *= p; vv.z *= p; vv.w *= p;
    } else {
      int t = u * 64 + (row - 64);
      int st = rot ? ((t + 63) & TMASK) : t;
      vv = *(const float4*)(vb + (size_t)st * DH + c4);
    }
    ushort4 o4;
    o4.x = f2bf(vv.x); o4.y = f2bf(vv.y); o4.z = f2bf(vv.z); o4.w = f2bf(vv.w);
    *(ushort4*)(sV + row * 64 + c4) = o4;
  }
  __syncthreads();

  // ---- dots: rows r_i = ty+16i (4), cols c_j = tx+16j (8) ----
  int tx = tid & 15, ty = tid >> 4;
  float acc[4][8];
#pragma unroll
  for (int i = 0; i < 4; ++i)
#pragma unroll
    for (int j = 0; j < 8; ++j) acc[i][j] = 0.f;

  for (int kk = 0; kk < 64; kk += 4) {
    float4 qf[4];
#pragma unroll
    for (int i = 0; i < 4; ++i) {
      ushort4 qu = *(const ushort4*)(sQ + (ty + 16 * i) * 64 + kk);
      qf[i] = make_float4(bf2f(qu.x), bf2f(qu.y), bf2f(qu.z), bf2f(qu.w));
    }
#pragma unroll
    for (int j = 0; j < 8; ++j) {
      float4 kf4 = *(const float4*)(sK + (tx + 16 * j) * 68 + kk);
#pragma unroll
      for (int i = 0; i < 4; ++i) {
        acc[i][j] = fmaf(qf[i].x, kf4.x, acc[i][j]);
        acc[i][j] = fmaf(qf[i].y, kf4.y, acc[i][j]);
        acc[i][j] = fmaf(qf[i].z, kf4.z, acc[i][j]);
        acc[i][j] = fmaf(qf[i].w, kf4.w, acc[i][j]);
      }
    }
  }

  // ---- mask + softmax (per row, 16 lanes per row hold 8 cols each) ----
  bool spec = rot && (u == 127);
#pragma unroll
  for (int i = 0; i < 4; ++i) {
    int r = ty + 16 * i;
    float mx = NEGF;
#pragma unroll
    for (int j = 0; j < 8; ++j) {
      int c = tx + 16 * j;
      bool vis = (c < 64) || ((c - 64) <= r);
      if (spec && r >= 1 && c <= 64) vis = false;
      if (!vis) acc[i][j] = -1e30f;
      mx = fmaxf(mx, acc[i][j]);
    }
    for (int off = 1; off < 16; off <<= 1) mx = fmaxf(mx, __shfl_xor(mx, off));
    float s = 0.f;
#pragma unroll
    for (int j = 0; j < 8; ++j) {
      float e = __expf(acc[i][j] - mx);
      acc[i][j] = e; s += e;
    }
    for (int off = 1; off < 16; off <<= 1) s += __shfl_xor(s, off);
    float inv = 1.f / s;
#pragma unroll
    for (int j = 0; j < 8; ++j) acc[i][j] *= inv;
  }

  __syncthreads();   // sQ/sK dead; safe to overwrite with sP
#pragma unroll
  for (int i = 0; i < 4; ++i)
#pragma unroll
    for (int j = 0; j < 8; ++j)
      sP[(ty + 16 * i) * 132 + tx + 16 * j] = acc[i][j];
  __syncthreads();

  // ---- P @ V2: out rows r_i = ty+16i, cols c = 4tx..4tx+3 ----
  float o[4][4];
#pragma unroll
  for (int i = 0; i < 4; ++i)
#pragma unroll
    for (int j = 0; j < 4; ++j) o[i][j] = 0.f;

  for (int cc = 0; cc < 128; cc += 4) {
    float4 pf[4];
#pragma unroll
    for (int i = 0; i < 4; ++i)
      pf[i] = *(const float4*)(sP + (ty + 16 * i) * 132 + cc);
    float4 vf[4];
#pragma unroll
    for (int s = 0; s < 4; ++s) {
      ushort4 vu = *(const ushort4*)(sV + (cc + s) * 64 + tx * 4);
      vf[s] = make_float4(bf2f(vu.x), bf2f(vu.y), bf2f(vu.z), bf2f(vu.w));
    }
#pragma unroll
    for (int i = 0; i < 4; ++i) {
      o[i][0] = fmaf(pf[i].x, vf[0].x, o[i][0]);
      o[i][0] = fmaf(pf[i].y, vf[1].x, o[i][0]);
      o[i][0] = fmaf(pf[i].z, vf[2].x, o[i][0]);
      o[i][0] = fmaf(pf[i].w, vf[3].x, o[i][0]);
      o[i][1] = fmaf(pf[i].x, vf[0].y, o[i][1]);
      o[i][1] = fmaf(pf[i].y, vf[1].y, o[i][1]);
      o[i][1] = fmaf(pf[i].z, vf[2].y, o[i][1]);
      o[i][1] = fmaf(pf[i].w, vf[3].y, o[i][1]);
      o[i][2] = fmaf(pf[i].x, vf[0].z, o[i][2]);
      o[i][2] = fmaf(pf[i].y, vf[1].z, o[i][2]);
      o[i][2] = fmaf(pf[i].z, vf[2].z, o[i][2]);
      o[i][2] = fmaf(pf[i].w, vf[3].z, o[i][2]);
      o[i][3] = fmaf(pf[i].x, vf[0].w, o[i][3]);
      o[i][3] = fmaf(pf[i].y, vf[1].w, o[i][3]);
      o[i][3] = fmaf(pf[i].z, vf[2].w, o[i][3]);
      o[i][3] = fmaf(pf[i].w, vf[3].w, o[i][3]);
    }
  }

  // ---- store with inverse rotation (same (t+63)&TMASK map) ----
#pragma unroll
  for (int i = 0; i < 4; ++i) {
    int r = ty + 16 * i;
    int t = u * 64 + r;
    int st = rot ? ((t + 63) & TMASK) : t;
    float4 ov = make_float4(o[i][0], o[i][1], o[i][2], o[i][3]);
    *(float4*)(ob + (size_t)st * DH + tx * 4) = ov;
  }
}

// ---------------------------------------------------------------------------
extern "C" void kernel_launch(void* const* d_in, const int* in_sizes, int n_in,
                              void* d_out, int out_size, void* d_ws, size_t ws_size,
                              hipStream_t stream) {
  const float* q     = (const float*)d_in[0];
  const float* k     = (const float*)d_in[1];
  const float* v     = (const float*)d_in[2];
  const float* sortW = (const float*)d_in[3];
  const float* nullk = (const float*)d_in[4];
  const float* nullv = (const float*)d_in[5];
  float* out = (float*)d_out;

  // workspace: segs 64*128*64 f32 (2 MB) | routeIdx 8192 i32 | routeP 8192 f32
  float* segs     = (float*)d_ws;
  int*   routeIdx = (int*)((char*)d_ws + (size_t)64 * 128 * 64 * 4);
  float* routeP   = (float*)((char*)d_ws + (size_t)64 * 128 * 64 * 4 + 32768);

  seg_sums_kernel<<<2048, 256, 0, stream>>>(k, segs);
  route_kernel<<<64, 256, 0, stream>>>(k, sortW, segs, routeIdx, routeP);
  attn_kernel<<<8192, 256, 0, stream>>>(q, k, v, nullk, nullv,
                                        routeIdx, routeP, out);
}

// Round 2
// 473.662 us; speedup vs baseline: 1.6045x; 1.6045x over previous
//
#include <hip/hip_runtime.h>

#define T     8192
#define DH    64
#define TMASK 8191
#define SCALE 0.044194173824159216f   // (h*dh)^-0.5 = 512^-0.5
#define NEGF  -3.402823466e38f

typedef __attribute__((ext_vector_type(8))) short bf16x8;
typedef __attribute__((ext_vector_type(4))) float f32x4;

static __device__ __forceinline__ unsigned short f2bf(float f) {
  unsigned int u = __float_as_uint(f);
  u += 0x7fffu + ((u >> 16) & 1u);      // round-to-nearest-even
  return (unsigned short)(u >> 16);
}

// ---------------------------------------------------------------------------
// Kernel A1: per-segment (bucket) sums of rotated k. grid = 64 bh * 32 chunks.
// ---------------------------------------------------------------------------
__global__ void __launch_bounds__(256) seg_sums_kernel(
    const float* __restrict__ k, float* __restrict__ segs) {
  int bid = blockIdx.x;
  int bhi = bid >> 5;
  int ch  = bid & 31;
  int hd  = bhi & 7;
  bool rot = hd >= 4;
  int tid = threadIdx.x;
  int sgl = tid >> 6;
  int c   = tid & 63;
  int sg  = ch * 4 + sgl;
  const float* kb = k + (size_t)bhi * T * DH;
  float sum = 0.f;
  int t0 = sg * 64;
  for (int s = 0; s < 64; ++s) {
    int t  = t0 + s;
    int st = rot ? ((t + 63) & TMASK) : t;
    sum += kb[(size_t)st * DH + c];
  }
  segs[((size_t)bhi * 128 + sg) * 64 + c] = sum;
}

// ---------------------------------------------------------------------------
// Kernel A2: routing, restructured for parallelism. grid = 64 bh * 8 = 512.
// Block handles rows u0..u0+15 of one bh. Stages segs in LDS (prefix is
// LDS-latency), recomputes exclusive prefix per row (redundant but cheap),
// then 16 rows x 128 cols matmul against W (L1-broadcast served).
// Emits routeIdx (0 = null, v>=1 = bucket v-1) and routeP.
// ---------------------------------------------------------------------------
__global__ void __launch_bounds__(256) route_kernel(
    const float* __restrict__ k, const float* __restrict__ sortW,
    const float* __restrict__ segs,
    int* __restrict__ routeIdx, float* __restrict__ routeP) {
  __shared__ float sSeg[128 * 64];   // 32 KB
  __shared__ float sX[16 * 128];     // 8 KB: [row][0:64]=cumavg, [64:128]=first
  int bid = blockIdx.x;
  int bhi = bid >> 3;
  int u0  = (bid & 7) * 16;
  int hd  = bhi & 7;
  bool rot = hd >= 4;
  int tid = threadIdx.x;
  const float* kb = k + (size_t)bhi * T * DH;
  const float* sg = segs + (size_t)bhi * 128 * 64;

  // stage segs (8192 floats, coalesced)
#pragma unroll
  for (int it = 0; it < 8; ++it) {
    int f4 = (it * 256 + tid) * 4;
    *(float4*)(sSeg + f4) = *(const float4*)(sg + f4);
  }
  // stage bucket-start k rows for our 16 rows
  {
    int r = tid >> 4, c4 = (tid & 15) << 2;
    int t = (u0 + r) * 64;
    int st = rot ? ((t + 63) & TMASK) : t;
    *(float4*)(sX + r * 128 + 64 + c4) = *(const float4*)(kb + (size_t)st * DH + c4);
  }
  __syncthreads();
  // exclusive prefix (serial over u, per-channel order matches round-1) + cumavg
  {
    int r = tid >> 4, c4 = (tid & 15) << 2;
    int u = u0 + r;
    float4 run = make_float4(0.f, 0.f, 0.f, 0.f);
    for (int uu = 0; uu < u; ++uu) {
      float4 sv = *(const float4*)(sSeg + uu * 64 + c4);
      run.x += sv.x; run.y += sv.y; run.z += sv.z; run.w += sv.w;
    }
    float4 first = *(const float4*)(sX + r * 128 + 64 + c4);
    float den = (float)(u * 64 + 1);
    float4 cum = make_float4((run.x + first.x) / den, (run.y + first.y) / den,
                             (run.z + first.z) / den, (run.w + first.w) / den);
    *(float4*)(sX + r * 128 + c4) = cum;
  }
  __syncthreads();

  // matmul: row u = u0+ty, cols c = tx+16j (col 128 always masked, skipped)
  int ty = tid >> 4, tx = tid & 15;
  int u = u0 + ty;
  const float* Wh = sortW + (size_t)hd * 128 * 129;
  float z[8] = {0.f, 0.f, 0.f, 0.f, 0.f, 0.f, 0.f, 0.f};
  for (int d = 0; d < 128; ++d) {
    float xv = sX[ty * 128 + d];
    const float* wr = Wh + (size_t)d * 129 + tx;
#pragma unroll
    for (int j = 0; j < 8; ++j) z[j] = fmaf(xv, wr[j * 16], z[j]);
  }
  // leaky_relu, causal softmax over c<=u, argmax over c<u
  float l[8];
  float mx = NEGF;
#pragma unroll
  for (int j = 0; j < 8; ++j) {
    int c = tx + 16 * j;
    float lv = z[j] >= 0.f ? z[j] : 0.01f * z[j];
    l[j] = lv;
    if (c <= u) mx = fmaxf(mx, lv);
  }
  for (int off = 1; off < 16; off <<= 1) mx = fmaxf(mx, __shfl_xor(mx, off));
  float se = 0.f;
#pragma unroll
  for (int j = 0; j < 8; ++j) {
    int c = tx + 16 * j;
    if (c <= u) se += __expf(l[j] - mx);
  }
  for (int off = 1; off < 16; off <<= 1) se += __shfl_xor(se, off);
  float bv = NEGF; int bi = 0x7fffffff;
#pragma unroll
  for (int j = 0; j < 8; ++j) {
    int c = tx + 16 * j;
    if (c < u && (l[j] > bv || (l[j] == bv && c < bi))) { bv = l[j]; bi = c; }
  }
  for (int off = 1; off < 16; off <<= 1) {
    float ov = __shfl_xor(bv, off); int oi = __shfl_xor(bi, off);
    if (ov > bv || (ov == bv && oi < bi)) { bv = ov; bi = oi; }
  }
  if (tx == 0) {
    if (u == 0) { routeIdx[bhi * 128] = 0; routeP[bhi * 128] = 0.f; }
    else {
      routeIdx[bhi * 128 + u] = bi;
      routeP[bhi * 128 + u]   = __expf(bv - mx) / se;
    }
  }
}

// ---------------------------------------------------------------------------
// Kernel B: MFMA attention. grid = 8192 blocks, 256 threads (4 waves).
// Wave w owns Q rows 16w..16w+15. S = Q.K2^T via mfma 16x16x32 bf16
// (8 n-tiles x 2 k-steps), softmax in C-layout, P->LDS (bf16, A-layout
// readback), O = P.V2 (4 n-tiles x 4 k-steps). V2 stored TRANSPOSED in LDS
// so B-fragments are contiguous ds_read_b128.
// LDS 45056 B -> 3 blocks/CU:
//   sQ  bf16 [64][72]   off 0      (9216 B)
//   sK  bf16 [128][72]  off 9216   (18432 B)
//   sVt bf16 [64][136]  off 27648  (17408 B)   (V2 transposed: [dh][128+pad])
//   sP  bf16 [64][136]  off 0      (17408 B, aliases dead sQ+sK)
// ---------------------------------------------------------------------------
__global__ void __launch_bounds__(256, 3) attn_kernel(
    const float* __restrict__ q, const float* __restrict__ k,
    const float* __restrict__ v,
    const float* __restrict__ nullk, const float* __restrict__ nullv,
    const int* __restrict__ routeIdx, const float* __restrict__ routeP,
    float* __restrict__ out) {
  __shared__ __align__(16) unsigned short smem[22528];
  unsigned short* sQ  = smem;           // [64][72]
  unsigned short* sK  = smem + 4608;    // [128][72]
  unsigned short* sVt = smem + 13824;   // [64][136]
  unsigned short* sP  = smem;           // [64][136] alias

  const int bid = blockIdx.x;
  const int u   = bid & 127;
  const int bhi = bid >> 7;
  const int hd  = bhi & 7;
  const bool rot = hd >= 4;
  const int tid = threadIdx.x;
  const float* qb = q + (size_t)bhi * T * DH;
  const float* kb = k + (size_t)bhi * T * DH;
  const float* vb = v + (size_t)bhi * T * DH;
  float* ob = out + (size_t)bhi * T * DH;
  const int   ridx = routeIdx[bhi * 128 + u];
  const float p    = routeP[bhi * 128 + u];
  const float* nkh = nullk + hd * DH;
  const float* nvh = nullv + hd * DH;

  // ---- Q (scaled) ----
#pragma unroll
  for (int it = 0; it < 4; ++it) {
    int flat = it * 256 + tid;
    int row = flat >> 4, c4 = (flat & 15) << 2;
    int t  = u * 64 + row;
    int st = rot ? ((t + 63) & TMASK) : t;
    float4 qv = *(const float4*)(qb + (size_t)st * DH + c4);
    ushort4 o4;
    o4.x = f2bf(qv.x * SCALE); o4.y = f2bf(qv.y * SCALE);
    o4.z = f2bf(qv.z * SCALE); o4.w = f2bf(qv.w * SCALE);
    *(ushort4*)(sQ + row * 72 + c4) = o4;
  }
  // ---- K2 (rows 0..63 routed*p, 64..127 causal) ----
#pragma unroll
  for (int it = 0; it < 8; ++it) {
    int flat = it * 256 + tid;
    int row = flat >> 4, c4 = (flat & 15) << 2;
    float4 kv;
    if (row < 64) {
      if (ridx == 0) kv = *(const float4*)(nkh + c4);
      else {
        int t = (ridx - 1) * 64 + row;
        int st = rot ? ((t + 63) & TMASK) : t;
        kv = *(const float4*)(kb + (size_t)st * DH + c4);
      }
      kv.x *= p; kv.y *= p; kv.z *= p; kv.w *= p;
    } else {
      int t = u * 64 + (row - 64);
      int st = rot ? ((t + 63) & TMASK) : t;
      kv = *(const float4*)(kb + (size_t)st * DH + c4);
    }
    ushort4 o4;
    o4.x = f2bf(kv.x); o4.y = f2bf(kv.y); o4.z = f2bf(kv.z); o4.w = f2bf(kv.w);
    *(ushort4*)(sK + row * 72 + c4) = o4;
  }
  // ---- V2, transposed into sVt[dh][row] ----
#pragma unroll
  for (int it = 0; it < 8; ++it) {
    int flat = it * 256 + tid;
    int row = flat >> 4, c4 = (flat & 15) << 2;
    float4 vv;
    if (row < 64) {
      if (ridx == 0) vv = *(const float4*)(nvh + c4);
      else {
        int t = (ridx - 1) * 64 + row;
        int st = rot ? ((t + 63) & TMASK) : t;
        vv = *(const float4*)(vb + (size_t)st * DH + c4);
      }
      vv.x *= p; vv.y *= p; vv.z *= p; vv.w *= p;
    } else {
      int t = u * 64 + (row - 64);
      int st = rot ? ((t + 63) & TMASK) : t;
      vv = *(const float4*)(vb + (size_t)st * DH + c4);
    }
    sVt[(c4 + 0) * 136 + row] = f2bf(vv.x);
    sVt[(c4 + 1) * 136 + row] = f2bf(vv.y);
    sVt[(c4 + 2) * 136 + row] = f2bf(vv.z);
    sVt[(c4 + 3) * 136 + row] = f2bf(vv.w);
  }
  __syncthreads();

  const int lane = tid & 63;
  const int w    = tid >> 6;
  const int col  = lane & 15;
  const int quad = lane >> 4;
  const int kofs = quad * 8;
  const int mrow = w * 16 + col;   // A-operand row (this wave's 16-row tile)

  // ---- S = Q . K2^T ----
  f32x4 acc[8];
#pragma unroll
  for (int j = 0; j < 8; ++j) acc[j] = (f32x4){0.f, 0.f, 0.f, 0.f};
  bf16x8 aq0 = *(const bf16x8*)(sQ + mrow * 72 + 0  + kofs);
  bf16x8 aq1 = *(const bf16x8*)(sQ + mrow * 72 + 32 + kofs);
#pragma unroll
  for (int j = 0; j < 8; ++j) {
    bf16x8 b0 = *(const bf16x8*)(sK + (j * 16 + col) * 72 + 0  + kofs);
    acc[j] = __builtin_amdgcn_mfma_f32_16x16x32_bf16(aq0, b0, acc[j], 0, 0, 0);
    bf16x8 b1 = *(const bf16x8*)(sK + (j * 16 + col) * 72 + 32 + kofs);
    acc[j] = __builtin_amdgcn_mfma_f32_16x16x32_bf16(aq1, b1, acc[j], 0, 0, 0);
  }

  // ---- mask + softmax (C-layout: row = 16w + 4*quad + reg, col = 16j + col) ----
  const bool spec = rot && (u == 127);
#pragma unroll
  for (int reg = 0; reg < 4; ++reg) {
    int r = w * 16 + quad * 4 + reg;
    float mx = -1e30f;
#pragma unroll
    for (int j = 0; j < 8; ++j) {
      int c = j * 16 + col;
      bool vis = (c < 64) || ((c - 64) <= r);
      if (spec && r >= 1 && c <= 64) vis = false;
      float val = vis ? acc[j][reg] : -1e30f;
      acc[j][reg] = val;
      mx = fmaxf(mx, val);
    }
#pragma unroll
    for (int off = 1; off < 16; off <<= 1) mx = fmaxf(mx, __shfl_xor(mx, off));
    float s = 0.f;
#pragma unroll
    for (int j = 0; j < 8; ++j) {
      float e = __expf(acc[j][reg] - mx);
      acc[j][reg] = e; s += e;
    }
#pragma unroll
    for (int off = 1; off < 16; off <<= 1) s += __shfl_xor(s, off);
    float inv = 1.f / s;
#pragma unroll
    for (int j = 0; j < 8; ++j) acc[j][reg] *= inv;
  }

  __syncthreads();   // everyone done reading sQ/sK before aliased sP writes
#pragma unroll
  for (int j = 0; j < 8; ++j)
#pragma unroll
    for (int reg = 0; reg < 4; ++reg)
      sP[(w * 16 + quad * 4 + reg) * 136 + j * 16 + col] = f2bf(acc[j][reg]);
  __syncthreads();

  // ---- O = P . V2 ----
  f32x4 oacc[4];
#pragma unroll
  for (int jt = 0; jt < 4; ++jt) oacc[jt] = (f32x4){0.f, 0.f, 0.f, 0.f};
#pragma unroll
  for (int ks = 0; ks < 4; ++ks) {
    bf16x8 ap = *(const bf16x8*)(sP + mrow * 136 + ks * 32 + kofs);
#pragma unroll
    for (int jt = 0; jt < 4; ++jt) {
      bf16x8 bv = *(const bf16x8*)(sVt + (jt * 16 + col) * 136 + ks * 32 + kofs);
      oacc[jt] = __builtin_amdgcn_mfma_f32_16x16x32_bf16(ap, bv, oacc[jt], 0, 0, 0);
    }
  }

  // ---- store (C-layout rows, inverse rotation) ----
#pragma unroll
  for (int reg = 0; reg < 4; ++reg) {
    int r = w * 16 + quad * 4 + reg;
    int t = u * 64 + r;
    int st = rot ? ((t + 63) & TMASK) : t;
    float* orow = ob + (size_t)st * DH;
#pragma unroll
    for (int jt = 0; jt < 4; ++jt)
      orow[jt * 16 + col] = oacc[jt][reg];
  }
}

// ---------------------------------------------------------------------------
extern "C" void kernel_launch(void* const* d_in, const int* in_sizes, int n_in,
                              void* d_out, int out_size, void* d_ws, size_t ws_size,
                              hipStream_t stream) {
  const float* q     = (const float*)d_in[0];
  const float* k     = (const float*)d_in[1];
  const float* v     = (const float*)d_in[2];
  const float* sortW = (const float*)d_in[3];
  const float* nullk = (const float*)d_in[4];
  const float* nullv = (const float*)d_in[5];
  float* out = (float*)d_out;

  float* segs     = (float*)d_ws;
  int*   routeIdx = (int*)((char*)d_ws + (size_t)64 * 128 * 64 * 4);
  float* routeP   = (float*)((char*)d_ws + (size_t)64 * 128 * 64 * 4 + 32768);

  seg_sums_kernel<<<2048, 256, 0, stream>>>(k, segs);
  route_kernel<<<512, 256, 0, stream>>>(k, sortW, segs, routeIdx, routeP);
  attn_kernel<<<8192, 256, 0, stream>>>(q, k, v, nullk, nullv,
                                        routeIdx, routeP, out);
}